// Round 1
// 381.347 us; speedup vs baseline: 1.0070x; 1.0070x over previous
//
#include <hip/hip_runtime.h>
#include <cstdint>
#include <cstddef>

// Problem constants (from reference)
#define BATCH 1024
#define S1 25
#define S2 10
#define FDIM 256
#define HDIM 128
#define NCLS 41
#define MAXDEG 128

typedef __attribute__((ext_vector_type(8))) short bf16x8;
typedef __attribute__((ext_vector_type(4))) float f32x4;

// ---------------- Threefry-2x32 (bit-exact vs JAX partitionable; r1-verified) --------
__host__ __device__ static inline void tf2x32(uint32_t k0, uint32_t k1,
                                              uint32_t c0, uint32_t c1,
                                              uint32_t& o0, uint32_t& o1) {
  const uint32_t ks2 = k0 ^ k1 ^ 0x1BD11BDAu;
  uint32_t x0 = c0 + k0, x1 = c1 + k1;
#define TFR(r) { x0 += x1; x1 = (x1 << (r)) | (x1 >> (32 - (r))); x1 ^= x0; }
  TFR(13) TFR(15) TFR(26) TFR(6)
  x0 += k1;  x1 += ks2 + 1u;
  TFR(17) TFR(29) TFR(16) TFR(24)
  x0 += ks2; x1 += k0 + 2u;
  TFR(13) TFR(15) TFR(26) TFR(6)
  x0 += k0;  x1 += k1 + 3u;
  TFR(17) TFR(29) TFR(16) TFR(24)
  x0 += k1;  x1 += ks2 + 4u;
  TFR(13) TFR(15) TFR(26) TFR(6)
  x0 += ks2; x1 += k0 + 5u;
#undef TFR
  o0 = x0; o1 = x1;
}

__device__ static inline uint32_t rand_bits_at(uint32_t kb0, uint32_t kb1, uint32_t j) {
  uint32_t o0, o1;
  tf2x32(kb0, kb1, 0u, j, o0, o1);
  return o0 ^ o1;
}

// fp32 -> bf16 (RNE) — values bit-preserved vs previous rounds
__device__ static inline ushort f2bf(float x) {
  uint32_t u = __float_as_uint(x);
  return (ushort)((u + 0x7fffu + ((u >> 16) & 1u)) >> 16);
}

// ================= K1: fused sampling + n2m + n1m/f1b + Wprep + h1m-zero =============
// blocks [0,6400): 4 waves x (sample hop1/hop2 inline, mean-of-10 feature rows -> bf16 n2m)
// blocks [6400,6656): 4 waves x (per-b mean-of-25 hop1 rows -> fp32 n1m, AND emit each
//                     hop1 row as bf16 into f1b — bit-identical to K2's old f2bf gather)
// blocks [6656,6912): Ws1/Wn1 -> bf16 transposed WbT[h*128+n][k]
// blocks [6912,7168): zero h1m (1 MB)
__global__ __launch_bounds__(256)
void prep_kernel(const int* __restrict__ node_ids, const float* __restrict__ feat,
                 const int* __restrict__ adj,
                 const float* __restrict__ Ws1, const float* __restrict__ Wn1,
                 ushort* __restrict__ n2m, float* __restrict__ n1m,
                 ushort* __restrict__ f1b, ushort* __restrict__ WbT,
                 float* __restrict__ h1m,
                 uint32_t kb1_0, uint32_t kb1_1, uint32_t kb2_0, uint32_t kb2_1) {
  const int blk = blockIdx.x;
  const int t = threadIdx.x;
  if (blk < 6400) {
    const int wave = t >> 6, lane = t & 63;
    const int g = blk * 4 + wave;          // 0..25599
    const int b = g / S1;
    int hop1v = 0;
    if (lane == 0) {
      uint32_t c1 = rand_bits_at(kb1_0, kb1_1, (uint32_t)g) & (MAXDEG - 1);
      hop1v = adj[(size_t)node_ids[b] * MAXDEG + c1];
    }
    hop1v = __shfl(hop1v, 0, 64);
    int r2id = 0;
    if (lane < S2) {
      uint32_t c2 = rand_bits_at(kb2_0, kb2_1, (uint32_t)(g * S2 + lane)) & (MAXDEG - 1);
      r2id = adj[(size_t)hop1v * MAXDEG + c2];
    }
    float4 acc = make_float4(0.f, 0.f, 0.f, 0.f);
#pragma unroll
    for (int r = 0; r < S2; ++r) {
      int rid = __shfl(r2id, r, 64);
      float4 v = ((const float4*)(feat + (size_t)rid * FDIM))[lane];
      acc.x += v.x; acc.y += v.y; acc.z += v.z; acc.w += v.w;
    }
    const float inv = 1.f / S2;
    ushort4 o;
    o.x = f2bf(acc.x * inv); o.y = f2bf(acc.y * inv);
    o.z = f2bf(acc.z * inv); o.w = f2bf(acc.w * inv);
    *(ushort4*)(n2m + (size_t)g * FDIM + lane * 4) = o;
  } else if (blk < 6656) {
    const int wave = t >> 6, lane = t & 63;
    const int b = (blk - 6400) * 4 + wave; // 0..1023
    int h1v = 0;
    if (lane < S1) {
      uint32_t c1 = rand_bits_at(kb1_0, kb1_1, (uint32_t)(b * S1 + lane)) & (MAXDEG - 1);
      h1v = adj[(size_t)node_ids[b] * MAXDEG + c1];
    }
    float4 acc = make_float4(0.f, 0.f, 0.f, 0.f);
#pragma unroll
    for (int r = 0; r < S1; ++r) {
      int rid = __shfl(h1v, r, 64);
      float4 v = ((const float4*)(feat + (size_t)rid * FDIM))[lane];
      acc.x += v.x; acc.y += v.y; acc.z += v.z; acc.w += v.w;
      // emit bf16 copy of this hop1 row (bit-identical to the old K2 gather+pack)
      ushort4 o;
      o.x = f2bf(v.x); o.y = f2bf(v.y); o.z = f2bf(v.z); o.w = f2bf(v.w);
      *(ushort4*)(f1b + (size_t)(b * S1 + r) * FDIM + lane * 4) = o;
    }
    const float inv = 1.f / S1;
    acc.x *= inv; acc.y *= inv; acc.z *= inv; acc.w *= inv;
    ((float4*)(n1m + (size_t)b * FDIM))[lane] = acc;
  } else if (blk < 6912) {
    const int idx = blk - 6656;            // h*128+n
    const int h = idx >> 7, n = idx & 127;
    const float* W = h ? Wn1 : Ws1;
    WbT[(size_t)idx * FDIM + t] = f2bf(W[(size_t)t * HDIM + n]);
  } else {
    const int i = (blk - 6912) * 256 + t;  // 65536 float4 = 1 MB
    ((float4*)h1m)[i] = make_float4(0.f, 0.f, 0.f, 0.f);
  }
}

// ================= K2: bf16 MFMA layer-1 GEMM + relu + S1-mean =======================
// grid (400, 2). A = (half ? n2m : f1b) — both pre-packed bf16, sequential int4 loads.
// B = WbT[half]. Epilogue: relu + per-b mean via atomics.
__global__ __launch_bounds__(256, 3)
void mfma_h1_kernel(const ushort* __restrict__ f1b, const ushort* __restrict__ n2m,
                    const ushort* __restrict__ WbT, float* __restrict__ h1m) {
  const int half = blockIdx.y;
  const ushort* Amat = half ? n2m : f1b;
  const ushort* Bmat = WbT + (size_t)half * HDIM * FDIM;
  const int m0 = blockIdx.x * 64;
  const int tid = threadIdx.x;
  const int wave = tid >> 6;
  const int lane = tid & 63;
  const int lq = lane >> 4;
  const int lr = lane & 15;

  __shared__ ushort As[64][40];
  __shared__ ushort Bs[128][40];
  __shared__ float  Cs[64][132];

  f32x4 acc[4][2];
#pragma unroll
  for (int rt = 0; rt < 4; ++rt)
#pragma unroll
    for (int ct = 0; ct < 2; ++ct) acc[rt][ct] = (f32x4)(0.f);

  for (int k0 = 0; k0 < FDIM; k0 += 32) {
    const int row = tid >> 2, kc = (tid & 3) * 8;
    {
      int4 v = *(const int4*)(Amat + (size_t)(m0 + row) * FDIM + k0 + kc);
      *(int4*)&As[row][kc] = v;
    }
#pragma unroll
    for (int i = 0; i < 2; ++i) {
      int idx = tid + i * 256;
      int n = idx >> 2, kc2 = (idx & 3) * 8;
      int4 v = *(const int4*)(Bmat + (size_t)n * FDIM + k0 + kc2);
      *(int4*)&Bs[n][kc2] = v;
    }
    __syncthreads();

    bf16x8 af[4];
#pragma unroll
    for (int rt = 0; rt < 4; ++rt)
      af[rt] = *(const bf16x8*)&As[rt * 16 + lr][lq * 8];
#pragma unroll
    for (int ct = 0; ct < 2; ++ct) {
      bf16x8 bf = *(const bf16x8*)&Bs[wave * 32 + ct * 16 + lr][lq * 8];
#pragma unroll
      for (int rt = 0; rt < 4; ++rt)
        acc[rt][ct] = __builtin_amdgcn_mfma_f32_16x16x32_bf16(af[rt], bf, acc[rt][ct], 0, 0, 0);
    }
    __syncthreads();
  }

#pragma unroll
  for (int rt = 0; rt < 4; ++rt)
#pragma unroll
    for (int ct = 0; ct < 2; ++ct)
#pragma unroll
      for (int r = 0; r < 4; ++r)
        Cs[rt * 16 + lq * 4 + r][wave * 32 + ct * 16 + lr] = fmaxf(acc[rt][ct][r], 0.f);
  __syncthreads();

  if (tid < 128) {
    const int c = tid;
    const int coff = half * HDIM + c;
    float s = 0.f;
    int curb = m0 / S1;
    for (int m = 0; m < 64; ++m) {
      int b = (m0 + m) / S1;
      if (b != curb) {
        atomicAdd(&h1m[(size_t)curb * (2 * HDIM) + coff], s * (1.f / S1));
        s = 0.f; curb = b;
      }
      s += Cs[m][c];
    }
    atomicAdd(&h1m[(size_t)curb * (2 * HDIM) + coff], s * (1.f / S1));
  }
}

// ================= K3: fused layer1-self + layer2 + l2norm + logits + softmax ========
// 512 blocks x 256 thr; block handles 2 batch rows (2 blocks/CU). Wp/bp staged in LDS.
__global__ __launch_bounds__(256)
void tail_kernel(const int* __restrict__ node_ids, const float* __restrict__ feat,
                 const float* __restrict__ n1m, const float* __restrict__ h1m,
                 const float* __restrict__ Ws1, const float* __restrict__ Wn1,
                 const float* __restrict__ Ws2, const float* __restrict__ Wn2,
                 const float* __restrict__ Wp, const float* __restrict__ bp,
                 float* __restrict__ out) {
  const int b0 = blockIdx.x * 2;
  const int t = threadIdx.x;
  const int wave = t >> 6, lane = t & 63;

  __shared__ float A0[2][256];   // f0 rows
  __shared__ float A1[2][256];   // n1m rows
  __shared__ float H1[2][256];   // h1m rows
  __shared__ float H0[2][256];   // relu(layer1-self)
  __shared__ float HN[2][256];   // l2-normalized hh
  __shared__ float WpL[2 * HDIM * NCLS];  // 41984 B
  __shared__ float bpL[NCLS];
  __shared__ float red[4][2];    // [wave][r]
  __shared__ float scl[2];
  __shared__ float lg[2][48];
  __shared__ float sm[2][2];

  if (wave < 2) {
    const int r = wave;
    const int nid = node_ids[b0 + r];
    ((float4*)A0[r])[lane] = ((const float4*)(feat + (size_t)nid * FDIM))[lane];
    ((float4*)A1[r])[lane] = ((const float4*)(n1m + (size_t)(b0 + r) * FDIM))[lane];
  } else {
    const int r = wave - 2;
    ((float4*)H1[r])[lane] = ((const float4*)(h1m + (size_t)(b0 + r) * FDIM))[lane];
  }
  // stage Wp (2624 float4) + bp
  for (int i = t; i < (2 * HDIM * NCLS) / 4; i += 256)
    ((float4*)WpL)[i] = ((const float4*)Wp)[i];
  if (t < NCLS) bpL[t] = bp[t];
  __syncthreads();

  const int h = t >> 7, c = t & 127;
  // phase 1: h0 = relu([f0@Ws1 ; n1m@Wn1]), column t, 2 rows
  {
    const float* W = h ? Wn1 : Ws1;
    const float* Ap = h ? &A1[0][0] : &A0[0][0];
    float acc0 = 0.f, acc1 = 0.f;
#pragma unroll 4
    for (int k4 = 0; k4 < 64; ++k4) {
      float w0 = W[(size_t)(k4 * 4 + 0) * HDIM + c];
      float w1 = W[(size_t)(k4 * 4 + 1) * HDIM + c];
      float w2 = W[(size_t)(k4 * 4 + 2) * HDIM + c];
      float w3 = W[(size_t)(k4 * 4 + 3) * HDIM + c];
      float4 a0 = ((const float4*)(Ap))[k4];
      float4 a1 = ((const float4*)(Ap + 256))[k4];
      acc0 += a0.x * w0 + a0.y * w1 + a0.z * w2 + a0.w * w3;
      acc1 += a1.x * w0 + a1.y * w1 + a1.z * w2 + a1.w * w3;
    }
    H0[0][t] = fmaxf(acc0, 0.f);
    H0[1][t] = fmaxf(acc1, 0.f);
  }
  __syncthreads();

  // phase 2: hh = [H0@Ws2 ; H1@Wn2] (no act), column t, 2 rows
  float hv0, hv1;
  {
    const float* W = h ? Wn2 : Ws2;
    const float* Ap = h ? &H1[0][0] : &H0[0][0];
    float acc0 = 0.f, acc1 = 0.f;
#pragma unroll 4
    for (int k4 = 0; k4 < 64; ++k4) {
      float w0 = W[(size_t)(k4 * 4 + 0) * HDIM + c];
      float w1 = W[(size_t)(k4 * 4 + 1) * HDIM + c];
      float w2 = W[(size_t)(k4 * 4 + 2) * HDIM + c];
      float w3 = W[(size_t)(k4 * 4 + 3) * HDIM + c];
      float4 a0 = ((const float4*)(Ap))[k4];
      float4 a1 = ((const float4*)(Ap + 256))[k4];
      acc0 += a0.x * w0 + a0.y * w1 + a0.z * w2 + a0.w * w3;
      acc1 += a1.x * w0 + a1.y * w1 + a1.z * w2 + a1.w * w3;
    }
    hv0 = acc0; hv1 = acc1;
  }

  // phase 3: l2 normalize per row
  {
    float s0 = hv0 * hv0, s1 = hv1 * hv1;
#pragma unroll
    for (int off = 32; off; off >>= 1) {
      s0 += __shfl_xor(s0, off, 64);
      s1 += __shfl_xor(s1, off, 64);
    }
    if (lane == 0) { red[wave][0] = s0; red[wave][1] = s1; }
  }
  __syncthreads();
  if (t < 2) {
    float tot = red[0][t] + red[1][t] + red[2][t] + red[3][t];
    scl[t] = rsqrtf(fmaxf(tot, 1e-12f));
  }
  __syncthreads();
  HN[0][t] = hv0 * scl[0];
  HN[1][t] = hv1 * scl[1];
  __syncthreads();

  // phase 4: logits — 82 dot-256's split across 4-lane groups, quad shfl reduce
  {
    const int g = t >> 2, q = t & 3;
    for (int p = g; p < 2 * NCLS; p += 64) {
      const int rr = (p >= NCLS) ? 1 : 0;
      const int cc = p - rr * NCLS;
      float s = 0.f;
#pragma unroll 8
      for (int k = 0; k < 64; ++k)
        s += HN[rr][q * 64 + k] * WpL[(size_t)(q * 64 + k) * NCLS + cc];
      s += __shfl_xor(s, 1, 64);
      s += __shfl_xor(s, 2, 64);
      if (q == 0) lg[rr][cc] = s + bpL[cc];
    }
  }
  __syncthreads();
  if (t < 2) {
    float m = -1e30f;
    for (int i = 0; i < NCLS; ++i) m = fmaxf(m, lg[t][i]);
    float s = 0.f;
    for (int i = 0; i < NCLS; ++i) s += expf(lg[t][i] - m);
    sm[t][0] = m; sm[t][1] = s;
  }
  __syncthreads();
  if (t < 2 * NCLS) {
    const int rr = (t >= NCLS) ? 1 : 0;
    const int cc = t - rr * NCLS;
    out[(size_t)(b0 + rr) * NCLS + cc] = expf(lg[rr][cc] - sm[rr][0]) / sm[rr][1];
  }
}

// ================= launch ============================================================
extern "C" void kernel_launch(void* const* d_in, const int* in_sizes, int n_in,
                              void* d_out, int out_size, void* d_ws, size_t ws_size,
                              hipStream_t stream) {
  const int*   node_ids = (const int*)d_in[0];
  const float* features = (const float*)d_in[1];
  const int*   adj      = (const int*)d_in[2];
  const float* Ws1      = (const float*)d_in[3];
  const float* Wn1      = (const float*)d_in[4];
  const float* Ws2      = (const float*)d_in[5];
  const float* Wn2      = (const float*)d_in[6];
  const float* Wp       = (const float*)d_in[7];
  const float* bp       = (const float*)d_in[8];
  float* out = (float*)d_out;

  char* ws = (char*)d_ws;
  ushort* n2m  = (ushort*)(ws + 0);           // 25600x256 bf16  (12.5 MB)
  ushort* f1b  = (ushort*)(ws + 13107200);    // 25600x256 bf16  (12.5 MB)
  ushort* WbT  = (ushort*)(ws + 26214400);    // 2x128x256 bf16  (128 KB)
  float*  n1m  = (float*)(ws + 26345472);     // 1024x256 f32    (1 MB)
  float*  h1m  = (float*)(ws + 27394048);     // 1024x256 f32    (1 MB)

  // JAX threefry key chain (bit-exact, r1-verified)
  uint32_t k1_0, k1_1, k2_0, k2_1, kb1_0, kb1_1, kb2_0, kb2_1;
  tf2x32(0u, 42u, 0u, 0u, k1_0, k1_1);
  tf2x32(0u, 42u, 0u, 1u, k2_0, k2_1);
  tf2x32(k1_0, k1_1, 0u, 1u, kb1_0, kb1_1);
  tf2x32(k2_0, k2_1, 0u, 1u, kb2_0, kb2_1);

  prep_kernel<<<7168, 256, 0, stream>>>(node_ids, features, adj, Ws1, Wn1,
                                        n2m, n1m, f1b, WbT, h1m,
                                        kb1_0, kb1_1, kb2_0, kb2_1);

  dim3 gBig(BATCH * S1 / 64, 2);
  mfma_h1_kernel<<<gBig, 256, 0, stream>>>(f1b, n2m, WbT, h1m);

  tail_kernel<<<BATCH / 2, 256, 0, stream>>>(node_ids, features, n1m, h1m,
                                             Ws1, Wn1, Ws2, Wn2, Wp, bp, out);
}

// Round 2
// 380.223 us; speedup vs baseline: 1.0100x; 1.0030x over previous
//
#include <hip/hip_runtime.h>
#include <cstdint>
#include <cstddef>

// Problem constants (from reference)
#define BATCH 1024
#define S1 25
#define S2 10
#define FDIM 256
#define HDIM 128
#define NCLS 41
#define MAXDEG 128

typedef __attribute__((ext_vector_type(8))) short bf16x8;
typedef __attribute__((ext_vector_type(4))) float f32x4;

// ---------------- Threefry-2x32 (bit-exact vs JAX partitionable; r1-verified) --------
__host__ __device__ static inline void tf2x32(uint32_t k0, uint32_t k1,
                                              uint32_t c0, uint32_t c1,
                                              uint32_t& o0, uint32_t& o1) {
  const uint32_t ks2 = k0 ^ k1 ^ 0x1BD11BDAu;
  uint32_t x0 = c0 + k0, x1 = c1 + k1;
#define TFR(r) { x0 += x1; x1 = (x1 << (r)) | (x1 >> (32 - (r))); x1 ^= x0; }
  TFR(13) TFR(15) TFR(26) TFR(6)
  x0 += k1;  x1 += ks2 + 1u;
  TFR(17) TFR(29) TFR(16) TFR(24)
  x0 += ks2; x1 += k0 + 2u;
  TFR(13) TFR(15) TFR(26) TFR(6)
  x0 += k0;  x1 += k1 + 3u;
  TFR(17) TFR(29) TFR(16) TFR(24)
  x0 += k1;  x1 += ks2 + 4u;
  TFR(13) TFR(15) TFR(26) TFR(6)
  x0 += ks2; x1 += k0 + 5u;
#undef TFR
  o0 = x0; o1 = x1;
}

__device__ static inline uint32_t rand_bits_at(uint32_t kb0, uint32_t kb1, uint32_t j) {
  uint32_t o0, o1;
  tf2x32(kb0, kb1, 0u, j, o0, o1);
  return o0 ^ o1;
}

// fp32 -> bf16 (RNE) — values bit-preserved vs previous rounds
__device__ static inline ushort f2bf(float x) {
  uint32_t u = __float_as_uint(x);
  return (ushort)((u + 0x7fffu + ((u >> 16) & 1u)) >> 16);
}

// ================= K1: WbT transpose (2x128 rows of 256 bf16) ========================
// WbT[h*128+n][k] = bf16(W[k][n]); tiny (128 KB), runs in ~3 us.
__global__ __launch_bounds__(256)
void wprep_kernel(const float* __restrict__ Ws1, const float* __restrict__ Wn1,
                  ushort* __restrict__ WbT) {
  const int idx = blockIdx.x;            // 0..255 = h*128 + n
  const int h = idx >> 7, n = idx & 127;
  const float* W = h ? Wn1 : Ws1;
  WbT[(size_t)idx * FDIM + threadIdx.x] = f2bf(W[(size_t)threadIdx.x * HDIM + n]);
}

// ================= K2: mega kernel — one block per batch row =========================
// Per block (256 thr / 4 waves):
//   A) sample 25 hop1 ids (threefry, bit-exact counters b*25+s1)
//   B) sample 250 hop2 ids; load f0; zero-pad A-tile rows 25..31
//   C) gather: per wave, s1-strided: f1 row -> n1 partial + bf16 As0[s1];
//      10 f2 rows -> mean -> bf16 As1[s1]   (~276 KB reads, the BW floor)
//   D) two MFMA GEMMs 32x256 @ WbT-half (B-frags in registers from L2-hot WbT),
//      relu + column mean over rows 0..24 via shfl_xor(16/32) -> H1M (no atomics)
//   E) tail: h0 GEMV, layer2 GEMV, l2norm, logits, softmax -> out[b]
__global__ __launch_bounds__(256, 3)
void mega_kernel(const int* __restrict__ node_ids, const float* __restrict__ feat,
                 const int* __restrict__ adj, const ushort* __restrict__ WbT,
                 const float* __restrict__ Ws1, const float* __restrict__ Wn1,
                 const float* __restrict__ Ws2, const float* __restrict__ Wn2,
                 const float* __restrict__ Wp, const float* __restrict__ bp,
                 float* __restrict__ out,
                 uint32_t kb1_0, uint32_t kb1_1, uint32_t kb2_0, uint32_t kb2_1) {
  const int b = blockIdx.x;
  const int t = threadIdx.x;
  const int wave = t >> 6, lane = t & 63;
  const int lq = lane >> 4, lr = lane & 15;

  __shared__ int    hop1s[S1];
  __shared__ int    hop2s[S1 * S2];
  __shared__ ushort As0[8][32][40];   // f1 bf16, k-chunked (chunk=32 k)
  __shared__ ushort As1[8][32][40];   // n2m bf16
  __shared__ float  F0[FDIM];
  __shared__ float  N1[4][FDIM];      // per-wave n1 partials; N1[0] -> combined n1m
  __shared__ float  H1M[2 * HDIM];    // mean_s1(h1)
  __shared__ float  H0[2 * HDIM];     // relu(layer1-self)
  __shared__ float  HN[2 * HDIM];     // l2-normalized h
  __shared__ float  red[4];
  __shared__ float  lg[NCLS];
  __shared__ float  smx[2];

  const int nid = node_ids[b];

  // ---- A: hop1 sampling ----
  if (t < S1) {
    uint32_t c1 = rand_bits_at(kb1_0, kb1_1, (uint32_t)(b * S1 + t)) & (MAXDEG - 1);
    hop1s[t] = adj[(size_t)nid * MAXDEG + c1];
  }
  __syncthreads();

  // ---- B: hop2 sampling + f0 load + A-tile zero pad (rows 25..31, cols 0..31) ----
  if (t < S1 * S2) {
    const int s1 = t / S2, j = t - s1 * S2;
    uint32_t c2 = rand_bits_at(kb2_0, kb2_1, (uint32_t)((b * S1 + s1) * S2 + j)) & (MAXDEG - 1);
    hop2s[t] = adj[(size_t)hop1s[s1] * MAXDEG + c2];
  }
  if (t < 64) ((float4*)F0)[t] = ((const float4*)(feat + (size_t)nid * FDIM))[t];
  {
    ushort4 z; z.x = 0; z.y = 0; z.z = 0; z.w = 0;
    for (int i = t; i < 448; i += 256) {     // 7 rows x 8 chunks x 8 q-slots
      const int rc = i >> 3, q = i & 7;
      const int r = 25 + (rc >> 3), ch = rc & 7;
      *(ushort4*)&As0[ch][r][q * 4] = z;
      *(ushort4*)&As1[ch][r][q * 4] = z;
    }
  }
  __syncthreads();

  // ---- C: gather f1 + f2 means (wave handles s1 = wave, wave+4, ...) ----
  {
    float ax = 0.f, ay = 0.f, az = 0.f, aw = 0.f;
    for (int s1 = wave; s1 < S1; s1 += 4) {
      const int rid1 = hop1s[s1];
      float4 v = ((const float4*)(feat + (size_t)rid1 * FDIM))[lane];
      float bx = 0.f, by = 0.f, bz = 0.f, bw = 0.f;
#pragma unroll
      for (int r = 0; r < S2; ++r) {
        const int rid = hop2s[s1 * S2 + r];
        float4 w = ((const float4*)(feat + (size_t)rid * FDIM))[lane];
        bx += w.x; by += w.y; bz += w.z; bw += w.w;
      }
      ax += v.x; ay += v.y; az += v.z; aw += v.w;
      ushort4 o1;
      o1.x = f2bf(v.x); o1.y = f2bf(v.y); o1.z = f2bf(v.z); o1.w = f2bf(v.w);
      *(ushort4*)&As0[lane >> 3][s1][(lane & 7) * 4] = o1;
      const float inv2 = 1.f / S2;
      ushort4 o2;
      o2.x = f2bf(bx * inv2); o2.y = f2bf(by * inv2);
      o2.z = f2bf(bz * inv2); o2.w = f2bf(bw * inv2);
      *(ushort4*)&As1[lane >> 3][s1][(lane & 7) * 4] = o2;
    }
    float4 p; p.x = ax; p.y = ay; p.z = az; p.w = aw;
    ((float4*)N1[wave])[lane] = p;
  }
  __syncthreads();

  // combine n1m (elementwise, no race: thread t owns column t)
  {
    const float s = N1[0][t] + N1[1][t] + N1[2][t] + N1[3][t];
    N1[0][t] = s * (1.f / S1);
  }

  // ---- D: two MFMA GEMMs, no internal barriers ----
#pragma unroll 1
  for (int half = 0; half < 2; ++half) {
    const ushort* Bmat = WbT + (size_t)half * HDIM * FDIM;
    const ushort (*As)[32][40] = half ? As1 : As0;

    bf16x8 bfr[2][8];
#pragma unroll
    for (int ct = 0; ct < 2; ++ct)
#pragma unroll
      for (int k0 = 0; k0 < 8; ++k0)
        bfr[ct][k0] = *(const bf16x8*)(Bmat + (size_t)(wave * 32 + ct * 16 + lr) * FDIM
                                       + k0 * 32 + lq * 8);

    f32x4 acc[2][2];
#pragma unroll
    for (int rt = 0; rt < 2; ++rt)
#pragma unroll
      for (int ct = 0; ct < 2; ++ct) acc[rt][ct] = (f32x4)(0.f);

#pragma unroll
    for (int k0 = 0; k0 < 8; ++k0) {
      bf16x8 af0 = *(const bf16x8*)&As[k0][lr][lq * 8];
      bf16x8 af1 = *(const bf16x8*)&As[k0][16 + lr][lq * 8];
#pragma unroll
      for (int ct = 0; ct < 2; ++ct) {
        acc[0][ct] = __builtin_amdgcn_mfma_f32_16x16x32_bf16(af0, bfr[ct][k0], acc[0][ct], 0, 0, 0);
        acc[1][ct] = __builtin_amdgcn_mfma_f32_16x16x32_bf16(af1, bfr[ct][k0], acc[1][ct], 0, 0, 0);
      }
    }

    // relu + column mean over rows 0..24 (rows 25..31 are exact zeros; relu(0)=0)
#pragma unroll
    for (int ct = 0; ct < 2; ++ct) {
      float s = 0.f;
#pragma unroll
      for (int rt = 0; rt < 2; ++rt)
#pragma unroll
        for (int r = 0; r < 4; ++r)
          s += fmaxf(acc[rt][ct][r], 0.f);
      s += __shfl_xor(s, 16, 64);
      s += __shfl_xor(s, 32, 64);
      if (lq == 0) H1M[half * HDIM + wave * 32 + ct * 16 + lr] = s * (1.f / S1);
    }
  }
  __syncthreads();

  // ---- E: tail ----
  const int hh = t >> 7, c = t & 127;
  // phase 1: h0 = relu([f0@Ws1 ; n1m@Wn1]), column t
  {
    const float* W = hh ? Wn1 : Ws1;
    const float* Ap = hh ? N1[0] : F0;
    float acc = 0.f;
#pragma unroll 4
    for (int k4 = 0; k4 < 64; ++k4) {
      float4 a = ((const float4*)Ap)[k4];
      acc += a.x * W[(size_t)(k4 * 4 + 0) * HDIM + c]
           + a.y * W[(size_t)(k4 * 4 + 1) * HDIM + c]
           + a.z * W[(size_t)(k4 * 4 + 2) * HDIM + c]
           + a.w * W[(size_t)(k4 * 4 + 3) * HDIM + c];
    }
    H0[t] = fmaxf(acc, 0.f);
  }
  __syncthreads();

  // phase 2: h = [H0@Ws2 ; H1M@Wn2] (no act), column t
  float hv;
  {
    const float* W = hh ? Wn2 : Ws2;
    const float* Ap = hh ? H1M : H0;
    float acc = 0.f;
#pragma unroll 4
    for (int k4 = 0; k4 < 64; ++k4) {
      float4 a = ((const float4*)Ap)[k4];
      acc += a.x * W[(size_t)(k4 * 4 + 0) * HDIM + c]
           + a.y * W[(size_t)(k4 * 4 + 1) * HDIM + c]
           + a.z * W[(size_t)(k4 * 4 + 2) * HDIM + c]
           + a.w * W[(size_t)(k4 * 4 + 3) * HDIM + c];
    }
    hv = acc;
  }

  // phase 3: l2 normalize
  {
    float s = hv * hv;
#pragma unroll
    for (int off = 32; off; off >>= 1) s += __shfl_xor(s, off, 64);
    if (lane == 0) red[wave] = s;
  }
  __syncthreads();
  {
    const float scl = rsqrtf(fmaxf(red[0] + red[1] + red[2] + red[3], 1e-12f));
    HN[t] = hv * scl;
  }
  __syncthreads();

  // phase 4: logits — 41 dot-256's split across 4-lane groups, quad shfl reduce
  {
    const int g = t >> 2, q = t & 3;
    if (g < NCLS) {
      float s = 0.f;
#pragma unroll 8
      for (int k = 0; k < 64; ++k)
        s += HN[q * 64 + k] * Wp[(size_t)(q * 64 + k) * NCLS + g];
      s += __shfl_xor(s, 1, 64);
      s += __shfl_xor(s, 2, 64);
      if (q == 0) lg[g] = s + bp[g];
    }
  }
  __syncthreads();
  if (t == 0) {
    float m = -1e30f;
    for (int i = 0; i < NCLS; ++i) m = fmaxf(m, lg[i]);
    float ssum = 0.f;
    for (int i = 0; i < NCLS; ++i) ssum += expf(lg[i] - m);
    smx[0] = m; smx[1] = ssum;
  }
  __syncthreads();
  if (t < NCLS)
    out[(size_t)b * NCLS + t] = expf(lg[t] - smx[0]) / smx[1];
}

// ================= launch ============================================================
extern "C" void kernel_launch(void* const* d_in, const int* in_sizes, int n_in,
                              void* d_out, int out_size, void* d_ws, size_t ws_size,
                              hipStream_t stream) {
  const int*   node_ids = (const int*)d_in[0];
  const float* features = (const float*)d_in[1];
  const int*   adj      = (const int*)d_in[2];
  const float* Ws1      = (const float*)d_in[3];
  const float* Wn1      = (const float*)d_in[4];
  const float* Ws2      = (const float*)d_in[5];
  const float* Wn2      = (const float*)d_in[6];
  const float* Wp       = (const float*)d_in[7];
  const float* bp       = (const float*)d_in[8];
  float* out = (float*)d_out;

  ushort* WbT = (ushort*)d_ws;                // 2x128x256 bf16 (128 KB) — only ws use

  // JAX threefry key chain (bit-exact, r1-verified)
  uint32_t k1_0, k1_1, k2_0, k2_1, kb1_0, kb1_1, kb2_0, kb2_1;
  tf2x32(0u, 42u, 0u, 0u, k1_0, k1_1);
  tf2x32(0u, 42u, 0u, 1u, k2_0, k2_1);
  tf2x32(k1_0, k1_1, 0u, 1u, kb1_0, kb1_1);
  tf2x32(k2_0, k2_1, 0u, 1u, kb2_0, kb2_1);

  wprep_kernel<<<256, 256, 0, stream>>>(Ws1, Wn1, WbT);

  mega_kernel<<<BATCH, 256, 0, stream>>>(node_ids, features, adj, WbT,
                                         Ws1, Wn1, Ws2, Wn2, Wp, bp, out,
                                         kb1_0, kb1_1, kb2_0, kb2_1);
}